// Round 1
// baseline (193.754 us; speedup 1.0000x reference)
//
#include <hip/hip_runtime.h>

#define B 2
#define S 2048
#define D 512
#define H 8
#define KD 64

typedef __bf16 bf16_t;
typedef __bf16 bf16x8 __attribute__((ext_vector_type(8)));
typedef float f32x4 __attribute__((ext_vector_type(4)));

// ---------------------------------------------------------------------------
// Kernel 1: fused QKV projection.
//   out = (X @ W[h] + b[h]) * scale   (scale = 0.125 folded into Q only)
//   Q, K stored [B*H, S, 64] bf16 row-major; V stored transposed [B*H, 64, S].
// grid = (B*H*(S/64), 3), block = 256 (4 waves); wave w -> rows s0+16w, all 64 cols.
// ---------------------------------------------------------------------------
__global__ __launch_bounds__(256) void qkv_kernel(
    const float* __restrict__ q_in, const float* __restrict__ k_in, const float* __restrict__ v_in,
    const float* __restrict__ Wq, const float* __restrict__ Wk, const float* __restrict__ Wv,
    const float* __restrict__ bq, const float* __restrict__ bk, const float* __restrict__ bv,
    bf16_t* __restrict__ Qo, bf16_t* __restrict__ Ko, bf16_t* __restrict__ VTo)
{
    const int mat = blockIdx.y;
    const float* Xp   = (mat == 0) ? q_in : (mat == 1) ? k_in : v_in;
    const float* Wp   = (mat == 0) ? Wq   : (mat == 1) ? Wk   : Wv;
    const float* bias = (mat == 0) ? bq   : (mat == 1) ? bk   : bv;
    const float scale = (mat == 0) ? 0.125f : 1.0f;  // 1/sqrt(64) folded into Q

    const int stile = blockIdx.x & 31;        // S/64 = 32 tiles
    const int bh    = blockIdx.x >> 5;        // 0..15
    const int h     = bh & (H - 1);

    const int tid = threadIdx.x;
    const int wave = tid >> 6;
    const int lane = tid & 63;
    const int g = lane >> 4;                   // lane group 0..3
    const int c = lane & 15;

    const int row0 = stile * 64 + wave * 16;   // this wave's 16 rows (A row = lane&15)
    const float* xrow = Xp + ((size_t)bh * S + row0 + c) * D;  // note: bh = b*H+h, X is [B,S,D] -> need b only
    // careful: X is [B, S, D]; row index within full [B*S]: b*S + row0 + c
    const int b = bh >> 3;
    xrow = Xp + ((size_t)b * S + row0 + c) * D;

    const f32x4 zero = {0.f, 0.f, 0.f, 0.f};
    f32x4 acc[4] = {zero, zero, zero, zero};

    for (int k0 = 0; k0 < D; k0 += 32) {
        // A fragment: X[row0+c][k0 + g*8 + j], fp32 -> bf16
        bf16x8 a;
        {
            const float4 f0 = *reinterpret_cast<const float4*>(xrow + k0 + g * 8);
            const float4 f1 = *reinterpret_cast<const float4*>(xrow + k0 + g * 8 + 4);
            a[0] = (__bf16)f0.x; a[1] = (__bf16)f0.y; a[2] = (__bf16)f0.z; a[3] = (__bf16)f0.w;
            a[4] = (__bf16)f1.x; a[5] = (__bf16)f1.y; a[6] = (__bf16)f1.z; a[7] = (__bf16)f1.w;
        }
#pragma unroll
        for (int ct = 0; ct < 4; ++ct) {
            // B fragment: W[h][k0+g*8+j][ct*16+c]
            const float* wp = Wp + ((size_t)h * D + k0 + g * 8) * KD + ct * 16 + c;
            bf16x8 wf;
#pragma unroll
            for (int j = 0; j < 8; ++j) wf[j] = (__bf16)wp[(size_t)j * KD];
            acc[ct] = __builtin_amdgcn_mfma_f32_16x16x32_bf16(a, wf, acc[ct], 0, 0, 0);
        }
    }

#pragma unroll
    for (int ct = 0; ct < 4; ++ct) {
        const int col = ct * 16 + c;
        const float bval = bias[h * KD + col];
#pragma unroll
        for (int i = 0; i < 4; ++i) {
            const int r = row0 + g * 4 + i;    // D row = (lane>>4)*4 + reg
            const float v = (acc[ct][i] + bval) * scale;
            if (mat == 0)      Qo[((size_t)bh * S + r) * KD + col] = (__bf16)v;
            else if (mat == 1) Ko[((size_t)bh * S + r) * KD + col] = (__bf16)v;
            else               VTo[((size_t)bh * KD + col) * S + r] = (__bf16)v;
        }
    }
}

// ---------------------------------------------------------------------------
// Kernel 2: flash attention per (b,h). grid = B*H*(S/64), block 256.
// Wave owns 16 q-rows; loops KV in tiles of 32 with online softmax.
// Q pre-scaled by 1/8. ctx written bf16 to [B, S, H*64] (head-concat layout).
// ---------------------------------------------------------------------------
__global__ __launch_bounds__(256) void attn_kernel(
    const bf16_t* __restrict__ Q,   // [BH, S, 64]
    const bf16_t* __restrict__ Km,  // [BH, S, 64]
    const bf16_t* __restrict__ VT,  // [BH, 64, S]
    bf16_t* __restrict__ CTX)       // [B, S, H*64]
{
    __shared__ __bf16 lds_p[4][16][80];   // per-wave P tile, padded stride 80 (160B)

    const int stile = blockIdx.x & 31;
    const int bh    = blockIdx.x >> 5;
    const int b = bh >> 3, h = bh & (H - 1);

    const int tid = threadIdx.x;
    const int wave = tid >> 6;
    const int lane = tid & 63;
    const int g = lane >> 4;
    const int c = lane & 15;

    const int q0 = stile * 64 + wave * 16;

    // Q A-fragments for both k-steps of head dim 64
    bf16x8 aq0, aq1;
    {
        const bf16_t* qp = Q + ((size_t)bh * S + q0 + c) * KD;
        aq0 = *reinterpret_cast<const bf16x8*>(qp + g * 8);
        aq1 = *reinterpret_cast<const bf16x8*>(qp + 32 + g * 8);
    }

    const f32x4 zero = {0.f, 0.f, 0.f, 0.f};
    f32x4 acc[4] = {zero, zero, zero, zero};
    float m_run[4], l_run[4];
#pragma unroll
    for (int i = 0; i < 4; ++i) { m_run[i] = -1e30f; l_run[i] = 0.f; }

    __bf16* myP = &lds_p[wave][0][0];

    for (int kv0 = 0; kv0 < S; kv0 += 32) {
        // ---- scores: 16 q-rows x 32 kv ----
        f32x4 sc[2];
#pragma unroll
        for (int t2 = 0; t2 < 2; ++t2) {
            const bf16_t* kp = Km + ((size_t)bh * S + kv0 + t2 * 16 + c) * KD;
            bf16x8 bk0 = *reinterpret_cast<const bf16x8*>(kp + g * 8);
            bf16x8 bk1 = *reinterpret_cast<const bf16x8*>(kp + 32 + g * 8);
            f32x4 z = zero;
            z = __builtin_amdgcn_mfma_f32_16x16x32_bf16(aq0, bk0, z, 0, 0, 0);
            sc[t2] = __builtin_amdgcn_mfma_f32_16x16x32_bf16(aq1, bk1, z, 0, 0, 0);
        }

        // ---- online softmax: row stats live on regs, reduce over 16-lane group ----
        float pm[4];
#pragma unroll
        for (int i = 0; i < 4; ++i) pm[i] = fmaxf(sc[0][i], sc[1][i]);
#pragma unroll
        for (int mask = 1; mask < 16; mask <<= 1)
#pragma unroll
            for (int i = 0; i < 4; ++i) pm[i] = fmaxf(pm[i], __shfl_xor(pm[i], mask));

        float f[4], rs[4];
        f32x4 p0, p1;
#pragma unroll
        for (int i = 0; i < 4; ++i) {
            const float mn = fmaxf(m_run[i], pm[i]);
            f[i] = __expf(m_run[i] - mn);
            m_run[i] = mn;
            p0[i] = __expf(sc[0][i] - mn);
            p1[i] = __expf(sc[1][i] - mn);
            rs[i] = p0[i] + p1[i];
        }
#pragma unroll
        for (int mask = 1; mask < 16; mask <<= 1)
#pragma unroll
            for (int i = 0; i < 4; ++i) rs[i] += __shfl_xor(rs[i], mask);
#pragma unroll
        for (int i = 0; i < 4; ++i) l_run[i] = l_run[i] * f[i] + rs[i];
#pragma unroll
        for (int ct = 0; ct < 4; ++ct)
#pragma unroll
            for (int i = 0; i < 4; ++i) acc[ct][i] *= f[i];

        // ---- P (D-layout) -> LDS -> A-layout fragment ----
#pragma unroll
        for (int i = 0; i < 4; ++i) {
            myP[(g * 4 + i) * 80 + c]      = (__bf16)p0[i];
            myP[(g * 4 + i) * 80 + 16 + c] = (__bf16)p1[i];
        }
        asm volatile("s_waitcnt lgkmcnt(0)" ::: "memory");
        bf16x8 ap = *reinterpret_cast<const bf16x8*>(myP + c * 80 + g * 8);

        // ---- PV: ctx += P @ V ----
#pragma unroll
        for (int ct = 0; ct < 4; ++ct) {
            const bf16_t* vp = VT + ((size_t)bh * KD + ct * 16 + c) * S + kv0 + g * 8;
            bf16x8 bv = *reinterpret_cast<const bf16x8*>(vp);
            acc[ct] = __builtin_amdgcn_mfma_f32_16x16x32_bf16(ap, bv, acc[ct], 0, 0, 0);
        }
    }

    // normalize + store ctx (bf16) in head-concat layout [B, S, H*64]
#pragma unroll
    for (int ct = 0; ct < 4; ++ct)
#pragma unroll
        for (int i = 0; i < 4; ++i) {
            const float v = acc[ct][i] / l_run[i];
            CTX[((size_t)b * S + q0 + g * 4 + i) * (H * KD) + h * KD + ct * 16 + c] = (__bf16)v;
        }
}

// ---------------------------------------------------------------------------
// Kernel 3: output projection. out = CTX[4096x512](bf16) @ Wo[512x512] + bo.
// grid = (M/64)*(N/64) = 512, block 256.
// ---------------------------------------------------------------------------
__global__ __launch_bounds__(256) void out_proj_kernel(
    const bf16_t* __restrict__ CTX,
    const float* __restrict__ Wo,
    const float* __restrict__ bo,
    float* __restrict__ out)
{
    const int ntile = blockIdx.x & 7;          // D/64 = 8
    const int mtile = blockIdx.x >> 3;         // 64
    const int tid = threadIdx.x;
    const int wave = tid >> 6;
    const int lane = tid & 63;
    const int g = lane >> 4;
    const int c = lane & 15;

    const int row0 = mtile * 64 + wave * 16;
    const int n0 = ntile * 64;

    const f32x4 zero = {0.f, 0.f, 0.f, 0.f};
    f32x4 acc[4] = {zero, zero, zero, zero};

    const bf16_t* arow = CTX + (size_t)(row0 + c) * (H * KD);
    for (int k0 = 0; k0 < H * KD; k0 += 32) {
        bf16x8 a = *reinterpret_cast<const bf16x8*>(arow + k0 + g * 8);
#pragma unroll
        for (int ct = 0; ct < 4; ++ct) {
            const float* wp = Wo + (size_t)(k0 + g * 8) * D + n0 + ct * 16 + c;
            bf16x8 wf;
#pragma unroll
            for (int j = 0; j < 8; ++j) wf[j] = (__bf16)wp[(size_t)j * D];
            acc[ct] = __builtin_amdgcn_mfma_f32_16x16x32_bf16(a, wf, acc[ct], 0, 0, 0);
        }
    }

#pragma unroll
    for (int ct = 0; ct < 4; ++ct) {
        const int col = n0 + ct * 16 + c;
        const float bval = bo[col];
#pragma unroll
        for (int i = 0; i < 4; ++i)
            out[(size_t)(row0 + g * 4 + i) * D + col] = acc[ct][i] + bval;
    }
}

// ---------------------------------------------------------------------------
extern "C" void kernel_launch(void* const* d_in, const int* in_sizes, int n_in,
                              void* d_out, int out_size, void* d_ws, size_t ws_size,
                              hipStream_t stream) {
    const float* query = (const float*)d_in[0];
    const float* key_  = (const float*)d_in[1];
    const float* value = (const float*)d_in[2];
    const float* Wq = (const float*)d_in[3];
    const float* bq = (const float*)d_in[4];
    const float* Wk = (const float*)d_in[5];
    const float* bk = (const float*)d_in[6];
    const float* Wv = (const float*)d_in[7];
    const float* bv = (const float*)d_in[8];
    const float* Wo = (const float*)d_in[9];
    const float* bo = (const float*)d_in[10];
    float* out = (float*)d_out;

    const size_t nPerMat = (size_t)B * H * S * KD;   // 2,097,152 bf16 = 4 MB
    bf16_t* Qw   = (bf16_t*)d_ws;
    bf16_t* Kw   = Qw + nPerMat;
    bf16_t* VTw  = Kw + nPerMat;
    bf16_t* CTXw = VTw + nPerMat;                    // total 16 MB of ws

    dim3 grid1(B * H * (S / 64), 3);
    qkv_kernel<<<grid1, 256, 0, stream>>>(query, key_, value, Wq, Wk, Wv,
                                          bq, bk, bv, Qw, Kw, VTw);
    attn_kernel<<<B * H * (S / 64), 256, 0, stream>>>(Qw, Kw, VTw, CTXw);
    out_proj_kernel<<<(B * S / 64) * (D / 64), 256, 0, stream>>>(CTXw, Wo, bo, out);
}